// Round 7
// baseline (938.823 us; speedup 1.0000x reference)
//
#include <hip/hip_runtime.h>
#include <hip/hip_bf16.h>
#include <hip/hip_fp16.h>
#include <hip/hip_cooperative_groups.h>

namespace cg = cooperative_groups;

#define N_NODES 100000
#define DFEAT 128
#define SLAB 4096         // edges per partition block
#define BSHIFT 9          // 512 nodes per bucket
#define NBUCK 196         // ceil(100000/512)

// ---------------- ws layout (4-byte units) ----------------
// cnt    [0      , 100000)   written by coop phase E
// w16    [100000 , 132768)   4x fp16 weight matrices (W1l,W1r,W2l,W2r), cast in phase A
// bcnt   [180000 , 180196)   per-bucket edge counts (zeroed in phase A)
// bbase  [180200 , 180397)   exclusive scan of bcnt (+ total at [196])
// bcur   [180400 , 180596)   allocation cursors per bucket
// offs   [200000 , 300096)   written by phase E
// esrc   [300608 , 1900608)
// aggh   [1900608, 8300608)   first: int2 pairs buffer; then fp16 agg1 / h
// casth  [8300608, 14700608)  fp16 x_h, then agg2
#define WS_CNT      0
#define WS_W16      100000
#define WS_BCNT     180000
#define WS_BBASE    180200
#define WS_BCUR     180400
#define WS_OFFS     200000
#define WS_ESRC     300608
#define WS_AGGH     1900608
#define WS_CASTH    8300608

typedef _Float16 half8 __attribute__((ext_vector_type(8)));
typedef _Float16 half2v __attribute__((ext_vector_type(2)));
typedef float floatx4 __attribute__((ext_vector_type(4)));

// ---------- ONE cooperative preprocessing kernel (replaces memset+prep+bscan+phase2+phase3) ----------
// Phases separated by grid.sync(); every phase grid-strides so any co-resident grid is correct.
__global__ __launch_bounds__(256) void preprocess_coop(
    const float* __restrict__ x, __half* __restrict__ xh, int total4,
    const int* __restrict__ src, const int* __restrict__ dst,
    int* __restrict__ bcnt, int* __restrict__ bbase, int* __restrict__ bcur,
    const float* __restrict__ W1l, const float* __restrict__ W1r,
    const float* __restrict__ W2l, const float* __restrict__ W2r,
    __half* __restrict__ w16,
    int2* __restrict__ pairs, int* __restrict__ cnt, int* __restrict__ offs,
    int* __restrict__ esrc, int E, int bpart, int n)
{
    cg::grid_group grid = cg::this_grid();
    __shared__ union {
        int lh[NBUCK];                                     // phase B
        int bs[256];                                       // phase C
        struct { int lbase[NBUCK]; int lcur[NBUCK]; int lgb[NBUCK];
                 int sc[256]; int2 lp[SLAB]; } d;          // phase D (~35.3 KB)
        struct { int lcnt[512]; int sc[512]; int lexcl[512]; } e;  // phase E
    } sm;

    const int t = threadIdx.x;
    const int gtid = blockIdx.x * 256 + t;
    const int gsz = gridDim.x * 256;

    // ---- phase A: zero bcnt + cast W -> fp16 + cast x -> fp16 ----
    if (gtid < NBUCK) bcnt[gtid] = 0;
    if (gtid < 16384) {
        int m = gtid >> 12;            // matrix 0..3 (W1l,W1r,W2l,W2r)
        int off = gtid & 4095;
        const float* Wp = (m == 0) ? W1l : (m == 1) ? W1r : (m == 2) ? W2l : W2r;
        float4 v = ((const float4*)Wp)[off];
        __half2 h01 = __floats2half2_rn(v.x, v.y);
        __half2 h23 = __floats2half2_rn(v.z, v.w);
        uint2 o;
        o.x = *(unsigned int*)&h01;
        o.y = *(unsigned int*)&h23;
        ((uint2*)w16)[gtid] = o;
    }
    for (int i = gtid; i < total4; i += gsz) {
        float4 v = ((const float4*)x)[i];
        __half2 h01 = __floats2half2_rn(v.x, v.y);
        __half2 h23 = __floats2half2_rn(v.z, v.w);
        uint2 o;
        o.x = *(unsigned int*)&h01;
        o.y = *(unsigned int*)&h23;
        ((uint2*)xh)[i] = o;
    }
    __threadfence();
    grid.sync();

    // ---- phase B: histogram dst buckets into bcnt (LDS hist per slab) ----
    for (int sb = blockIdx.x; sb < bpart; sb += gridDim.x) {
        for (int i = t; i < NBUCK; i += 256) sm.lh[i] = 0;
        __syncthreads();
        int s0 = sb * SLAB, s1 = min(E, s0 + SLAB);
        for (int i = s0 + t; i < s1; i += 256)
            atomicAdd(&sm.lh[dst[i] >> BSHIFT], 1);
        __syncthreads();
        for (int i = t; i < NBUCK; i += 256)
            if (sm.lh[i] > 0) atomicAdd(&bcnt[i], sm.lh[i]);
        __syncthreads();
    }
    __threadfence();
    grid.sync();

    // ---- phase C: exclusive scan bcnt -> bbase, init bcur (block 0 only) ----
    if (blockIdx.x == 0) {
        int v = (t < NBUCK) ? bcnt[t] : 0;
        sm.bs[t] = v;
        __syncthreads();
        for (int d = 1; d < 256; d <<= 1) {
            int u = (t >= d) ? sm.bs[t - d] : 0;
            __syncthreads();
            sm.bs[t] += u;
            __syncthreads();
        }
        if (t < NBUCK) {
            int excl = sm.bs[t] - v;
            bbase[t] = excl;
            bcur[t] = excl;
        }
        if (t == 0) bbase[NBUCK] = E;
        __threadfence();
    }
    grid.sync();

    // ---- phase D: LDS counting-sort each slab by bucket; atomic base-grab per bucket ----
    for (int sb = blockIdx.x; sb < bpart; sb += gridDim.x) {
        for (int i = t; i < NBUCK; i += 256) sm.d.lbase[i] = 0;
        __syncthreads();
        int s0 = sb * SLAB, s1 = min(E, s0 + SLAB);
        for (int i = s0 + t; i < s1; i += 256)
            atomicAdd(&sm.d.lbase[dst[i] >> BSHIFT], 1);
        __syncthreads();
        int v = (t < NBUCK) ? sm.d.lbase[t] : 0;
        sm.d.sc[t] = v;
        __syncthreads();
        for (int d = 1; d < 256; d <<= 1) {
            int u = (t >= d) ? sm.d.sc[t - d] : 0;
            __syncthreads();
            sm.d.sc[t] += u;
            __syncthreads();
        }
        if (t < NBUCK) {
            int excl = sm.d.sc[t] - v;
            sm.d.lbase[t] = excl;
            sm.d.lcur[t] = excl;
            sm.d.lgb[t] = (v > 0) ? atomicAdd(&bcur[t], v) : 0;
        }
        __syncthreads();
        for (int i = s0 + t; i < s1; i += 256) {
            int dd = dst[i];
            int ss = src[i];
            int bk = dd >> BSHIFT;
            int pos = atomicAdd(&sm.d.lcur[bk], 1);
            sm.d.lp[pos] = make_int2(ss, dd);
        }
        __syncthreads();
        int m = s1 - s0;
        for (int i = t; i < m; i += 256) {
            int2 p = sm.d.lp[i];
            int bk = p.y >> BSHIFT;
            pairs[sm.d.lgb[bk] + (i - sm.d.lbase[bk])] = p;
        }
        __syncthreads();
    }
    __threadfence();
    grid.sync();

    // ---- phase E: per-bucket node hist + scan -> cnt/offs + CSR finalize ----
    // 256 threads handle 512 node counters (each thread owns t and t+256).
    for (int g = blockIdx.x; g < NBUCK; g += gridDim.x) {
        int node0 = g << BSHIFT;
        sm.e.lcnt[t] = 0;
        sm.e.lcnt[t + 256] = 0;
        __syncthreads();
        int S = bbase[g], Eg = bbase[g + 1];
        for (int i = S + t; i < Eg; i += 256)
            atomicAdd(&sm.e.lcnt[pairs[i].y - node0], 1);
        __syncthreads();
        int v0 = sm.e.lcnt[t], v1 = sm.e.lcnt[t + 256];
        sm.e.sc[t] = v0;
        sm.e.sc[t + 256] = v1;
        __syncthreads();
        for (int d = 1; d < 512; d <<= 1) {
            int u0 = (t >= d) ? sm.e.sc[t - d] : 0;
            int u1 = (t + 256 >= d) ? sm.e.sc[t + 256 - d] : 0;
            __syncthreads();
            sm.e.sc[t] += u0;
            sm.e.sc[t + 256] += u1;
            __syncthreads();
        }
        int e0 = sm.e.sc[t] - v0;
        int e1 = sm.e.sc[t + 256] - v1;
        sm.e.lexcl[t] = e0;
        sm.e.lexcl[t + 256] = e1;
        int nd0 = node0 + t, nd1 = node0 + t + 256;
        if (nd0 < n) { cnt[nd0] = v0; offs[nd0] = S + e0; }
        if (nd1 < n) { cnt[nd1] = v1; offs[nd1] = S + e1; }
        __syncthreads();
        for (int i = S + t; i < Eg; i += 256) {
            int2 p = pairs[i];
            int pos = atomicAdd(&sm.e.lexcl[p.y - node0], 1);
            esrc[S + pos] = p.x;
        }
        __syncthreads();
    }
}

// ---------- aggregate: one 16-lane group per node (4 nodes/wave) — round-3 proven ----------
#define ACC(c, r)                        \
    s[c][0] += *(half2v*)&(r).x;         \
    s[c][1] += *(half2v*)&(r).y;         \
    s[c][2] += *(half2v*)&(r).z;         \
    s[c][3] += *(half2v*)&(r).w;

__global__ void aggregate_kernel(const __half* __restrict__ feat, const int* __restrict__ esrc,
                                 const int* __restrict__ offs, const int* __restrict__ cnt,
                                 __half* __restrict__ agg, int n) {
    int wid = (blockIdx.x * blockDim.x + threadIdx.x) >> 6;
    int lane = threadIdx.x & 63;
    int grp = lane >> 4;            // 0..3: node slot within wave
    int l15 = lane & 15;
    int node = wid * 4 + grp;
    if (node >= n) return;
    int beg = offs[node];
    int deg = cnt[node];
    const _Float16* fbase = (const _Float16*)feat + l15 * 8;
    const int* ep = esrc + beg;

    half2v s[4][4];
#pragma unroll
    for (int c = 0; c < 4; c++)
#pragma unroll
        for (int k = 0; k < 4; k++) s[c][k] = (half2v)(_Float16)0;

    int j = 0;
    for (; j + 8 <= deg; j += 8) {
        int i0 = ep[j + 0], i1 = ep[j + 1], i2 = ep[j + 2], i3 = ep[j + 3];
        int i4 = ep[j + 4], i5 = ep[j + 5], i6 = ep[j + 6], i7 = ep[j + 7];
        uint4 r0 = *(const uint4*)(fbase + (size_t)i0 * DFEAT);
        uint4 r1 = *(const uint4*)(fbase + (size_t)i1 * DFEAT);
        uint4 r2 = *(const uint4*)(fbase + (size_t)i2 * DFEAT);
        uint4 r3 = *(const uint4*)(fbase + (size_t)i3 * DFEAT);
        uint4 r4 = *(const uint4*)(fbase + (size_t)i4 * DFEAT);
        uint4 r5 = *(const uint4*)(fbase + (size_t)i5 * DFEAT);
        uint4 r6 = *(const uint4*)(fbase + (size_t)i6 * DFEAT);
        uint4 r7 = *(const uint4*)(fbase + (size_t)i7 * DFEAT);
        ACC(0, r0) ACC(1, r1) ACC(2, r2) ACC(3, r3)
        ACC(0, r4) ACC(1, r5) ACC(2, r6) ACC(3, r7)
    }
    for (; j + 4 <= deg; j += 4) {
        int i0 = ep[j + 0], i1 = ep[j + 1], i2 = ep[j + 2], i3 = ep[j + 3];
        uint4 r0 = *(const uint4*)(fbase + (size_t)i0 * DFEAT);
        uint4 r1 = *(const uint4*)(fbase + (size_t)i1 * DFEAT);
        uint4 r2 = *(const uint4*)(fbase + (size_t)i2 * DFEAT);
        uint4 r3 = *(const uint4*)(fbase + (size_t)i3 * DFEAT);
        ACC(0, r0) ACC(1, r1) ACC(2, r2) ACC(3, r3)
    }
    if (j < deg) {
        int rem = deg - j;
        int i0 = ep[j];
        int i1 = ep[j + (rem > 1 ? 1 : 0)];
        int i2 = ep[j + (rem > 2 ? 2 : 0)];
        uint4 r0 = *(const uint4*)(fbase + (size_t)i0 * DFEAT);
        uint4 r1 = *(const uint4*)(fbase + (size_t)i1 * DFEAT);
        uint4 r2 = *(const uint4*)(fbase + (size_t)i2 * DFEAT);
        if (rem < 2) { r1.x = 0u; r1.y = 0u; r1.z = 0u; r1.w = 0u; }
        if (rem < 3) { r2.x = 0u; r2.y = 0u; r2.z = 0u; r2.w = 0u; }
        ACC(0, r0) ACC(1, r1) ACC(2, r2)
    }

    float scale = 1.0f / fmaxf((float)deg, 1.0f);
    float a[8];
#pragma unroll
    for (int k = 0; k < 4; k++) {
        a[2 * k]     = ((float)s[0][k].x + (float)s[1][k].x) + ((float)s[2][k].x + (float)s[3][k].x);
        a[2 * k + 1] = ((float)s[0][k].y + (float)s[1][k].y) + ((float)s[2][k].y + (float)s[3][k].y);
    }
    __half2 h0 = __floats2half2_rn(a[0] * scale, a[1] * scale);
    __half2 h1 = __floats2half2_rn(a[2] * scale, a[3] * scale);
    __half2 h2 = __floats2half2_rn(a[4] * scale, a[5] * scale);
    __half2 h3 = __floats2half2_rn(a[6] * scale, a[7] * scale);
    uint4 o;
    o.x = *(unsigned int*)&h0;
    o.y = *(unsigned int*)&h1;
    o.z = *(unsigned int*)&h2;
    o.w = *(unsigned int*)&h3;
    *(uint4*)(agg + (size_t)node * DFEAT + l15 * 8) = o;
}

// ---------- MFMA dual-GEMM: 64-node blocks, fp16 W pre-cast, prefetch ----------
template <bool NORM_RELU>
__global__ __launch_bounds__(256) void gemm64_kernel(
    const __half* __restrict__ A1_, const __half* __restrict__ A2_,
    const __half* __restrict__ Wl16, const __half* __restrict__ Wr16,
    const float* __restrict__ bias, float* __restrict__ out32,
    __half* __restrict__ out16, int n) {
    __shared__ __align__(16) _Float16 lw[128 * 136];   // 34.8 KB

    const _Float16* A1 = (const _Float16*)A1_;
    const _Float16* A2 = (const _Float16*)A2_;
    const _Float16* wl = (const _Float16*)Wl16;
    const _Float16* wr = (const _Float16*)Wr16;

    const int lane = threadIdx.x & 63;
    const int w = threadIdx.x >> 6;       // wave 0..3
    const int quad = lane >> 4;
    const int l15 = lane & 15;
    const int i0 = blockIdx.x * 64 + w * 16;
    int r = i0 + l15;
    if (r >= n) r = n - 1;
    const int kq = quad * 8;

    // prefetch B-fragments (agg rows) so they fly during Wl staging
    half8 bf[4];
#pragma unroll
    for (int k = 0; k < 4; k++)
        bf[k] = *(const half8*)(A1 + (size_t)r * DFEAT + k * 32 + kq);

    // stage Wl (fp16 copy, 8 uint4/thread)
    {
        int t = threadIdx.x;
        int row = t >> 1;
        int cb = (t & 1) * 64;
        const uint4* sp = (const uint4*)(wl + row * DFEAT + cb);
        uint4* dp = (uint4*)&lw[row * 136 + cb];
#pragma unroll
        for (int q = 0; q < 8; q++) dp[q] = sp[q];
    }
    __syncthreads();

    floatx4 acc[8];
#pragma unroll
    for (int ft = 0; ft < 8; ft++) acc[ft] = (floatx4){0.f, 0.f, 0.f, 0.f};

#pragma unroll
    for (int kci = 0; kci < 4; kci++) {
#pragma unroll
        for (int ft = 0; ft < 8; ft++) {
            half8 a = *(const half8*)&lw[(ft * 16 + l15) * 136 + kci * 32 + kq];
            acc[ft] = __builtin_amdgcn_mfma_f32_16x16x32_f16(a, bf[kci], acc[ft], 0, 0, 0);
        }
    }

    // prefetch root (self) fragments; they fly across the barrier/staging
    half8 xf[4];
#pragma unroll
    for (int k = 0; k < 4; k++)
        xf[k] = *(const half8*)(A2 + (size_t)r * DFEAT + k * 32 + kq);

    __syncthreads();   // all waves done reading Wl
    // stage Wr
    {
        int t = threadIdx.x;
        int row = t >> 1;
        int cb = (t & 1) * 64;
        const uint4* sp = (const uint4*)(wr + row * DFEAT + cb);
        uint4* dp = (uint4*)&lw[row * 136 + cb];
#pragma unroll
        for (int q = 0; q < 8; q++) dp[q] = sp[q];
    }
    __syncthreads();

#pragma unroll
    for (int kci = 0; kci < 4; kci++) {
#pragma unroll
        for (int ft = 0; ft < 8; ft++) {
            half8 a = *(const half8*)&lw[(ft * 16 + l15) * 136 + kci * 32 + kq];
            acc[ft] = __builtin_amdgcn_mfma_f32_16x16x32_f16(a, xf[kci], acc[ft], 0, 0, 0);
        }
    }

    // ---- epilogue: bias (+ normalize + relu) + store ----
    int node = i0 + l15;
    float v[8][4];
#pragma unroll
    for (int ft = 0; ft < 8; ft++) {
        const float4 bq = *(const float4*)(bias + ft * 16 + quad * 4);
        v[ft][0] = acc[ft][0] + bq.x;
        v[ft][1] = acc[ft][1] + bq.y;
        v[ft][2] = acc[ft][2] + bq.z;
        v[ft][3] = acc[ft][3] + bq.w;
    }
    if (NORM_RELU) {
        float ss = 0.f;
#pragma unroll
        for (int ft = 0; ft < 8; ft++)
#pragma unroll
            for (int q = 0; q < 4; q++) ss = fmaf(v[ft][q], v[ft][q], ss);
        ss += __shfl_xor(ss, 16);
        ss += __shfl_xor(ss, 32);
        float inv = 1.0f / fmaxf(sqrtf(ss), 1e-12f);
#pragma unroll
        for (int ft = 0; ft < 8; ft++)
#pragma unroll
            for (int q = 0; q < 4; q++) v[ft][q] = fmaxf(v[ft][q] * inv, 0.0f);
    }
    if (node < n) {
        if (NORM_RELU) {
            __half* op = (__half*)out16 + (size_t)node * DFEAT + quad * 4;
#pragma unroll
            for (int ft = 0; ft < 8; ft++) {
                __half2 h01 = __floats2half2_rn(v[ft][0], v[ft][1]);
                __half2 h23 = __floats2half2_rn(v[ft][2], v[ft][3]);
                uint2 o;
                o.x = *(unsigned int*)&h01;
                o.y = *(unsigned int*)&h23;
                *(uint2*)(op + ft * 16) = o;
            }
        } else {
            float* op = out32 + (size_t)node * DFEAT + quad * 4;
#pragma unroll
            for (int ft = 0; ft < 8; ft++)
                *(float4*)(op + ft * 16) = make_float4(v[ft][0], v[ft][1], v[ft][2], v[ft][3]);
        }
    }
}

extern "C" void kernel_launch(void* const* d_in, const int* in_sizes, int n_in,
                              void* d_out, int out_size, void* d_ws, size_t ws_size,
                              hipStream_t stream) {
    const float* x = (const float*)d_in[0];
    const int* edge_index = (const int*)d_in[1];
    const float* W1l = (const float*)d_in[2];
    const float* b1 = (const float*)d_in[3];
    const float* W1r = (const float*)d_in[4];
    const float* W2l = (const float*)d_in[5];
    const float* b2 = (const float*)d_in[6];
    const float* W2r = (const float*)d_in[7];
    float* out = (float*)d_out;

    int E = in_sizes[1] / 2;
    int n = in_sizes[0] / DFEAT;  // 100000

    int* ws = (int*)d_ws;
    int* cnt = ws + WS_CNT;
    __half* w16 = (__half*)(ws + WS_W16);
    int* bcnt = ws + WS_BCNT;
    int* bbase = ws + WS_BBASE;
    int* bcur = ws + WS_BCUR;
    int* offs = ws + WS_OFFS;
    int* esrc = ws + WS_ESRC;
    int2* pairs = (int2*)(ws + WS_AGGH);
    __half* aggh = (__half*)(ws + WS_AGGH);
    __half* casth = (__half*)(ws + WS_CASTH);

    const int* src = edge_index;
    const int* dst = edge_index + E;

    int bpart = (E + SLAB - 1) / SLAB;        // 391
    int total4 = n * DFEAT / 4;               // 3.2M float4

    // per-matrix fp16 views (order: W1l, W1r, W2l, W2r)
    __half* w1l16 = w16;
    __half* w1r16 = w16 + 16384;
    __half* w2l16 = w16 + 32768;
    __half* w2r16 = w16 + 49152;

    // cooperative grid sizing (cached): co-residency required for grid.sync()
    static int coopGrid = 0;
    if (coopGrid == 0) {
        int mb = 0;
        if (hipOccupancyMaxActiveBlocksPerMultiprocessor(
                &mb, reinterpret_cast<const void*>(&preprocess_coop), 256, 0) != hipSuccess ||
            mb < 1)
            mb = 2;  // conservative: 35.3 KB LDS certainly allows >= 2 blocks/CU
        int ncu = 0;
        if (hipDeviceGetAttribute(&ncu, hipDeviceAttributeMultiprocessorCount, 0) != hipSuccess ||
            ncu <= 0)
            ncu = 256;
        long g = (long)mb * ncu;
        coopGrid = (int)(g > 1024 ? 1024 : g);
        if (coopGrid < 256) coopGrid = 256;
    }

    void* cargs[] = {
        (void*)&x, (void*)&casth, (void*)&total4, (void*)&src, (void*)&dst,
        (void*)&bcnt, (void*)&bbase, (void*)&bcur,
        (void*)&W1l, (void*)&W1r, (void*)&W2l, (void*)&W2r, (void*)&w16,
        (void*)&pairs, (void*)&cnt, (void*)&offs, (void*)&esrc,
        (void*)&E, (void*)&bpart, (void*)&n};
    (void)hipLaunchCooperativeKernel(reinterpret_cast<const void*>(&preprocess_coop),
                                     dim3(coopGrid), dim3(256), cargs, 0, stream);

    const int nwaves = (n + 3) / 4;
    const int aggb = (nwaves * 64 + 255) / 256;     // 6250
    const int gemmb = (n + 63) / 64;                // 1563

    // layer 1: agg(x_h) -> aggh; h = relu(normalize(aggh@W1l^T + b1 + x_h@W1r^T)) -> fp16 aggh
    aggregate_kernel<<<aggb, 256, 0, stream>>>(casth, esrc, offs, cnt, aggh, n);
    gemm64_kernel<true><<<gemmb, 256, 0, stream>>>(aggh, casth, w1l16, w1r16, b1,
                                                   nullptr, aggh, n);

    // layer 2: agg(h) -> casth; out = casth@W2l^T + b2 + h@W2r^T (fp32 to d_out)
    aggregate_kernel<<<aggb, 256, 0, stream>>>(aggh, esrc, offs, cnt, casth, n);
    gemm64_kernel<false><<<gemmb, 256, 0, stream>>>(casth, aggh, w2l16, w2r16, b2,
                                                    out, nullptr, n);
}

// Round 8
// 622.495 us; speedup vs baseline: 1.5082x; 1.5082x over previous
//
#include <hip/hip_runtime.h>
#include <hip/hip_bf16.h>
#include <hip/hip_fp16.h>

#define N_NODES 100000
#define DFEAT 128

// ---------------- ws layout (4-byte units) ----------------
// cnt    [0      , 100000)   per-node degree (memset to 0, built by prep global atomics)
// w16    [100000 , 132768)   4x fp16 weight matrices (W1l,W1r,W2l,W2r), cast by prep
// offs   [200000 , 300096)   scan of cnt; scatter mutates to END offsets (beg = offs-cnt)
// esrc   [300608 , 1900608)  CSR edge sources
// aggh   [1900608, 8300608)  fp16 agg1 / h
// casth  [8300608, 14700608) fp16 x_h, then agg2
#define WS_CNT      0
#define WS_W16      100000
#define WS_OFFS     200000
#define WS_ESRC     300608
#define WS_AGGH     1900608
#define WS_CASTH    8300608

typedef _Float16 half8 __attribute__((ext_vector_type(8)));
typedef _Float16 half2v __attribute__((ext_vector_type(2)));
typedef float floatx4 __attribute__((ext_vector_type(4)));

// ---------- prep: cast x->fp16 + cast 4 W->fp16 + global-atomic degree histogram ----------
__global__ __launch_bounds__(256) void prep_kernel(const float* __restrict__ x,
                                                   __half* __restrict__ xh, int total4,
                                                   const int* __restrict__ dst,
                                                   int* __restrict__ cnt,
                                                   const float* __restrict__ W1l,
                                                   const float* __restrict__ W1r,
                                                   const float* __restrict__ W2l,
                                                   const float* __restrict__ W2r,
                                                   __half* __restrict__ w16,
                                                   int E, int castblocks) {
    int b = blockIdx.x;
    if (b < castblocks) {
        int i = b * 256 + threadIdx.x;
        if (i < total4) {
            float4 v = ((const float4*)x)[i];
            __half2 h01 = __floats2half2_rn(v.x, v.y);
            __half2 h23 = __floats2half2_rn(v.z, v.w);
            uint2 o;
            o.x = *(unsigned int*)&h01;
            o.y = *(unsigned int*)&h23;
            ((uint2*)xh)[i] = o;
        }
        return;
    }
    if (b < castblocks + 64) {
        int i = (b - castblocks) * 256 + threadIdx.x;   // [0, 16384)
        int m = i >> 12;                                 // matrix 0..3
        int off = i & 4095;
        const float* Wp = (m == 0) ? W1l : (m == 1) ? W1r : (m == 2) ? W2l : W2r;
        float4 v = ((const float4*)Wp)[off];
        __half2 h01 = __floats2half2_rn(v.x, v.y);
        __half2 h23 = __floats2half2_rn(v.z, v.w);
        uint2 o;
        o.x = *(unsigned int*)&h01;
        o.y = *(unsigned int*)&h23;
        ((uint2*)w16)[i] = o;
        return;
    }
    int hb = b - castblocks - 64;
    int s0 = hb * 1024, s1 = min(E, s0 + 1024);
    for (int i = s0 + threadIdx.x; i < s1; i += 256)
        atomicAdd(&cnt[dst[i]], 1);
}

// ---------- single-block scan: cnt[100K] -> exclusive offs[100K] ----------
__global__ __launch_bounds__(1024) void scan_kernel(const int* __restrict__ cnt,
                                                    int* __restrict__ offs, int n) {
    __shared__ int ps[1024];
    int t = threadIdx.x;
    int chunk = (n + 1023) / 1024;           // 98
    int s0 = t * chunk, s1 = min(n, s0 + chunk);
    int sum = 0;
    for (int i = s0; i < s1; i++) sum += cnt[i];
    ps[t] = sum;
    __syncthreads();
    for (int d = 1; d < 1024; d <<= 1) {
        int u = (t >= d) ? ps[t - d] : 0;
        __syncthreads();
        ps[t] += u;
        __syncthreads();
    }
    int run = ps[t] - sum;                   // exclusive prefix of this chunk
    for (int i = s0; i < s1; i++) {
        offs[i] = run;
        run += cnt[i];
    }
}

// ---------- scatter: CSR finalize via atomic cursors (offs mutates to END offsets) ----------
__global__ __launch_bounds__(256) void scatter_kernel(const int* __restrict__ src,
                                                      const int* __restrict__ dst,
                                                      int* __restrict__ offs,
                                                      int* __restrict__ esrc, int E) {
    int i = blockIdx.x * 256 + threadIdx.x;
    if (i < E) {
        int pos = atomicAdd(&offs[dst[i]], 1);
        esrc[pos] = src[i];
    }
}

// ---------- aggregate: one 16-lane group per node (4 nodes/wave) — round-3 proven ----------
// NOTE: offs holds END offsets after scatter; beg = offs[node] - cnt[node].
#define ACC(c, r)                        \
    s[c][0] += *(half2v*)&(r).x;         \
    s[c][1] += *(half2v*)&(r).y;         \
    s[c][2] += *(half2v*)&(r).z;         \
    s[c][3] += *(half2v*)&(r).w;

__global__ void aggregate_kernel(const __half* __restrict__ feat, const int* __restrict__ esrc,
                                 const int* __restrict__ offs, const int* __restrict__ cnt,
                                 __half* __restrict__ agg, int n) {
    int wid = (blockIdx.x * blockDim.x + threadIdx.x) >> 6;
    int lane = threadIdx.x & 63;
    int grp = lane >> 4;            // 0..3: node slot within wave
    int l15 = lane & 15;
    int node = wid * 4 + grp;
    if (node >= n) return;
    int deg = cnt[node];
    int beg = offs[node] - deg;
    const _Float16* fbase = (const _Float16*)feat + l15 * 8;
    const int* ep = esrc + beg;

    half2v s[4][4];
#pragma unroll
    for (int c = 0; c < 4; c++)
#pragma unroll
        for (int k = 0; k < 4; k++) s[c][k] = (half2v)(_Float16)0;

    int j = 0;
    for (; j + 8 <= deg; j += 8) {
        int i0 = ep[j + 0], i1 = ep[j + 1], i2 = ep[j + 2], i3 = ep[j + 3];
        int i4 = ep[j + 4], i5 = ep[j + 5], i6 = ep[j + 6], i7 = ep[j + 7];
        uint4 r0 = *(const uint4*)(fbase + (size_t)i0 * DFEAT);
        uint4 r1 = *(const uint4*)(fbase + (size_t)i1 * DFEAT);
        uint4 r2 = *(const uint4*)(fbase + (size_t)i2 * DFEAT);
        uint4 r3 = *(const uint4*)(fbase + (size_t)i3 * DFEAT);
        uint4 r4 = *(const uint4*)(fbase + (size_t)i4 * DFEAT);
        uint4 r5 = *(const uint4*)(fbase + (size_t)i5 * DFEAT);
        uint4 r6 = *(const uint4*)(fbase + (size_t)i6 * DFEAT);
        uint4 r7 = *(const uint4*)(fbase + (size_t)i7 * DFEAT);
        ACC(0, r0) ACC(1, r1) ACC(2, r2) ACC(3, r3)
        ACC(0, r4) ACC(1, r5) ACC(2, r6) ACC(3, r7)
    }
    for (; j + 4 <= deg; j += 4) {
        int i0 = ep[j + 0], i1 = ep[j + 1], i2 = ep[j + 2], i3 = ep[j + 3];
        uint4 r0 = *(const uint4*)(fbase + (size_t)i0 * DFEAT);
        uint4 r1 = *(const uint4*)(fbase + (size_t)i1 * DFEAT);
        uint4 r2 = *(const uint4*)(fbase + (size_t)i2 * DFEAT);
        uint4 r3 = *(const uint4*)(fbase + (size_t)i3 * DFEAT);
        ACC(0, r0) ACC(1, r1) ACC(2, r2) ACC(3, r3)
    }
    if (j < deg) {
        int rem = deg - j;
        int i0 = ep[j];
        int i1 = ep[j + (rem > 1 ? 1 : 0)];
        int i2 = ep[j + (rem > 2 ? 2 : 0)];
        uint4 r0 = *(const uint4*)(fbase + (size_t)i0 * DFEAT);
        uint4 r1 = *(const uint4*)(fbase + (size_t)i1 * DFEAT);
        uint4 r2 = *(const uint4*)(fbase + (size_t)i2 * DFEAT);
        if (rem < 2) { r1.x = 0u; r1.y = 0u; r1.z = 0u; r1.w = 0u; }
        if (rem < 3) { r2.x = 0u; r2.y = 0u; r2.z = 0u; r2.w = 0u; }
        ACC(0, r0) ACC(1, r1) ACC(2, r2)
    }

    float scale = 1.0f / fmaxf((float)deg, 1.0f);
    float a[8];
#pragma unroll
    for (int k = 0; k < 4; k++) {
        a[2 * k]     = ((float)s[0][k].x + (float)s[1][k].x) + ((float)s[2][k].x + (float)s[3][k].x);
        a[2 * k + 1] = ((float)s[0][k].y + (float)s[1][k].y) + ((float)s[2][k].y + (float)s[3][k].y);
    }
    __half2 h0 = __floats2half2_rn(a[0] * scale, a[1] * scale);
    __half2 h1 = __floats2half2_rn(a[2] * scale, a[3] * scale);
    __half2 h2 = __floats2half2_rn(a[4] * scale, a[5] * scale);
    __half2 h3 = __floats2half2_rn(a[6] * scale, a[7] * scale);
    uint4 o;
    o.x = *(unsigned int*)&h0;
    o.y = *(unsigned int*)&h1;
    o.z = *(unsigned int*)&h2;
    o.w = *(unsigned int*)&h3;
    *(uint4*)(agg + (size_t)node * DFEAT + l15 * 8) = o;
}

// ---------- MFMA dual-GEMM: 64-node blocks, fp16 W pre-cast, prefetch ----------
template <bool NORM_RELU>
__global__ __launch_bounds__(256) void gemm64_kernel(
    const __half* __restrict__ A1_, const __half* __restrict__ A2_,
    const __half* __restrict__ Wl16, const __half* __restrict__ Wr16,
    const float* __restrict__ bias, float* __restrict__ out32,
    __half* __restrict__ out16, int n) {
    __shared__ __align__(16) _Float16 lw[128 * 136];   // 34.8 KB

    const _Float16* A1 = (const _Float16*)A1_;
    const _Float16* A2 = (const _Float16*)A2_;
    const _Float16* wl = (const _Float16*)Wl16;
    const _Float16* wr = (const _Float16*)Wr16;

    const int lane = threadIdx.x & 63;
    const int w = threadIdx.x >> 6;       // wave 0..3
    const int quad = lane >> 4;
    const int l15 = lane & 15;
    const int i0 = blockIdx.x * 64 + w * 16;
    int r = i0 + l15;
    if (r >= n) r = n - 1;
    const int kq = quad * 8;

    // prefetch B-fragments (agg rows) so they fly during Wl staging
    half8 bf[4];
#pragma unroll
    for (int k = 0; k < 4; k++)
        bf[k] = *(const half8*)(A1 + (size_t)r * DFEAT + k * 32 + kq);

    // stage Wl (fp16 copy, 8 uint4/thread)
    {
        int t = threadIdx.x;
        int row = t >> 1;
        int cb = (t & 1) * 64;
        const uint4* sp = (const uint4*)(wl + row * DFEAT + cb);
        uint4* dp = (uint4*)&lw[row * 136 + cb];
#pragma unroll
        for (int q = 0; q < 8; q++) dp[q] = sp[q];
    }
    __syncthreads();

    floatx4 acc[8];
#pragma unroll
    for (int ft = 0; ft < 8; ft++) acc[ft] = (floatx4){0.f, 0.f, 0.f, 0.f};

#pragma unroll
    for (int kci = 0; kci < 4; kci++) {
#pragma unroll
        for (int ft = 0; ft < 8; ft++) {
            half8 a = *(const half8*)&lw[(ft * 16 + l15) * 136 + kci * 32 + kq];
            acc[ft] = __builtin_amdgcn_mfma_f32_16x16x32_f16(a, bf[kci], acc[ft], 0, 0, 0);
        }
    }

    // prefetch root (self) fragments; they fly across the barrier/staging
    half8 xf[4];
#pragma unroll
    for (int k = 0; k < 4; k++)
        xf[k] = *(const half8*)(A2 + (size_t)r * DFEAT + k * 32 + kq);

    __syncthreads();   // all waves done reading Wl
    // stage Wr
    {
        int t = threadIdx.x;
        int row = t >> 1;
        int cb = (t & 1) * 64;
        const uint4* sp = (const uint4*)(wr + row * DFEAT + cb);
        uint4* dp = (uint4*)&lw[row * 136 + cb];
#pragma unroll
        for (int q = 0; q < 8; q++) dp[q] = sp[q];
    }
    __syncthreads();

#pragma unroll
    for (int kci = 0; kci < 4; kci++) {
#pragma unroll
        for (int ft = 0; ft < 8; ft++) {
            half8 a = *(const half8*)&lw[(ft * 16 + l15) * 136 + kci * 32 + kq];
            acc[ft] = __builtin_amdgcn_mfma_f32_16x16x32_f16(a, xf[kci], acc[ft], 0, 0, 0);
        }
    }

    // ---- epilogue: bias (+ normalize + relu) + store ----
    int node = i0 + l15;
    float v[8][4];
#pragma unroll
    for (int ft = 0; ft < 8; ft++) {
        const float4 bq = *(const float4*)(bias + ft * 16 + quad * 4);
        v[ft][0] = acc[ft][0] + bq.x;
        v[ft][1] = acc[ft][1] + bq.y;
        v[ft][2] = acc[ft][2] + bq.z;
        v[ft][3] = acc[ft][3] + bq.w;
    }
    if (NORM_RELU) {
        float ss = 0.f;
#pragma unroll
        for (int ft = 0; ft < 8; ft++)
#pragma unroll
            for (int q = 0; q < 4; q++) ss = fmaf(v[ft][q], v[ft][q], ss);
        ss += __shfl_xor(ss, 16);
        ss += __shfl_xor(ss, 32);
        float inv = 1.0f / fmaxf(sqrtf(ss), 1e-12f);
#pragma unroll
        for (int ft = 0; ft < 8; ft++)
#pragma unroll
            for (int q = 0; q < 4; q++) v[ft][q] = fmaxf(v[ft][q] * inv, 0.0f);
    }
    if (node < n) {
        if (NORM_RELU) {
            __half* op = (__half*)out16 + (size_t)node * DFEAT + quad * 4;
#pragma unroll
            for (int ft = 0; ft < 8; ft++) {
                __half2 h01 = __floats2half2_rn(v[ft][0], v[ft][1]);
                __half2 h23 = __floats2half2_rn(v[ft][2], v[ft][3]);
                uint2 o;
                o.x = *(unsigned int*)&h01;
                o.y = *(unsigned int*)&h23;
                *(uint2*)(op + ft * 16) = o;
            }
        } else {
            float* op = out32 + (size_t)node * DFEAT + quad * 4;
#pragma unroll
            for (int ft = 0; ft < 8; ft++)
                *(float4*)(op + ft * 16) = make_float4(v[ft][0], v[ft][1], v[ft][2], v[ft][3]);
        }
    }
}

extern "C" void kernel_launch(void* const* d_in, const int* in_sizes, int n_in,
                              void* d_out, int out_size, void* d_ws, size_t ws_size,
                              hipStream_t stream) {
    const float* x = (const float*)d_in[0];
    const int* edge_index = (const int*)d_in[1];
    const float* W1l = (const float*)d_in[2];
    const float* b1 = (const float*)d_in[3];
    const float* W1r = (const float*)d_in[4];
    const float* W2l = (const float*)d_in[5];
    const float* b2 = (const float*)d_in[6];
    const float* W2r = (const float*)d_in[7];
    float* out = (float*)d_out;

    int E = in_sizes[1] / 2;
    int n = in_sizes[0] / DFEAT;  // 100000

    int* ws = (int*)d_ws;
    int* cnt = ws + WS_CNT;
    __half* w16 = (__half*)(ws + WS_W16);
    int* offs = ws + WS_OFFS;
    int* esrc = ws + WS_ESRC;
    __half* aggh = (__half*)(ws + WS_AGGH);
    __half* casth = (__half*)(ws + WS_CASTH);

    const int* src = edge_index;
    const int* dst = edge_index + E;

    int total4 = n * DFEAT / 4;               // 3.2M float4
    int castblocks = (total4 + 255) / 256;    // 12500
    int histblocks = (E + 1023) / 1024;       // 1563

    // per-matrix fp16 views (order: W1l, W1r, W2l, W2r)
    __half* w1l16 = w16;
    __half* w1r16 = w16 + 16384;
    __half* w2l16 = w16 + 32768;
    __half* w2r16 = w16 + 49152;

    hipMemsetAsync(cnt, 0, n * sizeof(int), stream);

    prep_kernel<<<castblocks + 64 + histblocks, 256, 0, stream>>>(
        x, casth, total4, dst, cnt, W1l, W1r, W2l, W2r, w16, E, castblocks);
    scan_kernel<<<1, 1024, 0, stream>>>(cnt, offs, n);
    scatter_kernel<<<(E + 255) / 256, 256, 0, stream>>>(src, dst, offs, esrc, E);

    const int nwaves = (n + 3) / 4;
    const int aggb = (nwaves * 64 + 255) / 256;     // 6250
    const int gemmb = (n + 63) / 64;                // 1563

    // layer 1: agg(x_h) -> aggh; h = relu(normalize(aggh@W1l^T + b1 + x_h@W1r^T)) -> fp16 aggh
    aggregate_kernel<<<aggb, 256, 0, stream>>>(casth, esrc, offs, cnt, aggh, n);
    gemm64_kernel<true><<<gemmb, 256, 0, stream>>>(aggh, casth, w1l16, w1r16, b1,
                                                   nullptr, aggh, n);

    // layer 2: agg(h) -> casth; out = casth@W2l^T + b2 + h@W2r^T (fp32 to d_out)
    aggregate_kernel<<<aggb, 256, 0, stream>>>(aggh, esrc, offs, cnt, casth, n);
    gemm64_kernel<false><<<gemmb, 256, 0, stream>>>(casth, aggh, w2l16, w2r16, b2,
                                                    out, nullptr, n);
}

// Round 9
// 404.817 us; speedup vs baseline: 2.3191x; 1.5377x over previous
//
#include <hip/hip_runtime.h>
#include <hip/hip_bf16.h>
#include <hip/hip_fp16.h>

#define N_NODES 100000
#define DFEAT 128
#define SLAB 4096         // edges per partition block
#define BSHIFT 9          // 512 nodes per bucket
#define NBUCK 196         // ceil(100000/512)

// ---------------- ws layout (4-byte units) ----------------
// cnt    [0      , 100000)   written by phase3
// w16    [100000 , 132768)   4x fp16 weight matrices (W1l,W1r,W2l,W2r), cast by prep
// bcnt   [180000 , 180196)   per-bucket edge counts (global atomics; memset to 0)
// bbase  [180200 , 180397)   exclusive scan of bcnt (+ total at [196])
// bcur   [180400 , 180596)   allocation cursors per bucket
// offs   [200000 , 300096)   written by phase3
// esrc   [300608 , 1900608)
// pairs  [1900608, ...)      packed ((dst&511)<<17)|src, 1 int per edge; then fp16 agg1 / h
// casth  [8300608, 14700608) fp16 x_h, then agg2
#define WS_CNT      0
#define WS_W16      100000
#define WS_BCNT     180000
#define WS_BBASE    180200
#define WS_BCUR     180400
#define WS_OFFS     200000
#define WS_ESRC     300608
#define WS_AGGH     1900608
#define WS_CASTH    8300608

typedef _Float16 half8 __attribute__((ext_vector_type(8)));
typedef _Float16 half2v __attribute__((ext_vector_type(2)));
typedef float floatx4 __attribute__((ext_vector_type(4)));

// ---------- fused prep: cast x->fp16 + cast 4 W matrices->fp16 + slab bucket hist ----------
__global__ __launch_bounds__(256) void prep_kernel(const float* __restrict__ x,
                                                   __half* __restrict__ xh, int total4,
                                                   const int* __restrict__ dst,
                                                   int* __restrict__ bcnt,
                                                   const float* __restrict__ W1l,
                                                   const float* __restrict__ W1r,
                                                   const float* __restrict__ W2l,
                                                   const float* __restrict__ W2r,
                                                   __half* __restrict__ w16,
                                                   int E, int bpart, int castblocks) {
    __shared__ int lh[NBUCK];
    int b = blockIdx.x;
    if (b < castblocks) {
        int i = b * 256 + threadIdx.x;
        if (i < total4) {
            float4 v = ((const float4*)x)[i];
            __half2 h01 = __floats2half2_rn(v.x, v.y);
            __half2 h23 = __floats2half2_rn(v.z, v.w);
            uint2 o;
            o.x = *(unsigned int*)&h01;
            o.y = *(unsigned int*)&h23;
            ((uint2*)xh)[i] = o;
        }
        return;
    }
    if (b < castblocks + 64) {
        // cast the 4 weight matrices: 4 * 4096 float4 = 16384 float4 over 64 blocks
        int i = (b - castblocks) * 256 + threadIdx.x;   // [0, 16384)
        int m = i >> 12;                                 // matrix 0..3
        int off = i & 4095;                              // float4 index within matrix
        const float* Wp = (m == 0) ? W1l : (m == 1) ? W1r : (m == 2) ? W2l : W2r;
        float4 v = ((const float4*)Wp)[off];
        __half2 h01 = __floats2half2_rn(v.x, v.y);
        __half2 h23 = __floats2half2_rn(v.z, v.w);
        uint2 o;
        o.x = *(unsigned int*)&h01;
        o.y = *(unsigned int*)&h23;
        ((uint2*)w16)[i] = o;
        return;
    }
    int bb = b - castblocks - 64;
    for (int i = threadIdx.x; i < NBUCK; i += 256) lh[i] = 0;
    __syncthreads();
    int s0 = bb * SLAB, s1 = min(E, s0 + SLAB);
    for (int i = s0 + threadIdx.x; i < s1; i += 256)
        atomicAdd(&lh[dst[i] >> BSHIFT], 1);
    __syncthreads();
    for (int i = threadIdx.x; i < NBUCK; i += 256)
        if (lh[i] > 0) atomicAdd(&bcnt[i], lh[i]);
}

// ---------- tiny bucket scan: bcnt[196] -> bbase (exclusive), init bcur ----------
__global__ void bscan_kernel(const int* __restrict__ bcnt, int* __restrict__ bbase,
                             int* __restrict__ bcur, int E) {
    __shared__ int s[256];
    int t = threadIdx.x;
    int v = (t < NBUCK) ? bcnt[t] : 0;
    s[t] = v;
    __syncthreads();
    for (int d = 1; d < 256; d <<= 1) {
        int u = (t >= d) ? s[t - d] : 0;
        __syncthreads();
        s[t] += u;
        __syncthreads();
    }
    if (t < NBUCK) {
        int excl = s[t] - v;
        bbase[t] = excl;
        bcur[t] = excl;
    }
    if (t == 0) bbase[NBUCK] = E;
}

// ---------- phase 2: LDS counting-sort slab by bucket; write PACKED pairs ----------
// packed = ((dst & 511) << 17) | src   (src < 2^17, bucket-local dst 9 bits)
__global__ __launch_bounds__(256) void phase2_kernel(const int* __restrict__ src,
                                                     const int* __restrict__ dst,
                                                     int* __restrict__ bcur,
                                                     int* __restrict__ pairs,
                                                     int E) {
    __shared__ int lbase[NBUCK];
    __shared__ int lcur[NBUCK];
    __shared__ int lgb[NBUCK];
    __shared__ int sc[256];
    __shared__ int2 lp[SLAB];   // 32 KB
    int b = blockIdx.x;
    int t = threadIdx.x;
    for (int i = t; i < NBUCK; i += 256) lbase[i] = 0;
    __syncthreads();
    int s0 = b * SLAB, s1 = min(E, s0 + SLAB);
    for (int i = s0 + t; i < s1; i += 256)
        atomicAdd(&lbase[dst[i] >> BSHIFT], 1);
    __syncthreads();
    int v = (t < NBUCK) ? lbase[t] : 0;
    sc[t] = v;
    __syncthreads();
    for (int d = 1; d < 256; d <<= 1) {
        int u = (t >= d) ? sc[t - d] : 0;
        __syncthreads();
        sc[t] += u;
        __syncthreads();
    }
    if (t < NBUCK) {
        int excl = sc[t] - v;
        lbase[t] = excl;
        lcur[t] = excl;
        lgb[t] = (v > 0) ? atomicAdd(&bcur[t], v) : 0;   // block's base within bucket
    }
    __syncthreads();
    for (int i = s0 + t; i < s1; i += 256) {
        int d = dst[i];
        int s = src[i];
        int bk = d >> BSHIFT;
        int pos = atomicAdd(&lcur[bk], 1);
        lp[pos] = make_int2(s, d);
    }
    __syncthreads();
    int m = s1 - s0;
    for (int i = t; i < m; i += 256) {
        int2 p = lp[i];
        int bk = p.y >> BSHIFT;
        pairs[lgb[bk] + (i - lbase[bk])] = ((p.y & 511) << 17) | p.x;
    }
}

// ---------- phase 3: per-bucket node hist (LDS) + scan -> cnt/offs + CSR finalize ----------
__global__ __launch_bounds__(512) void phase3_kernel(const int* __restrict__ pairs,
                                                     const int* __restrict__ bbase,
                                                     int* __restrict__ cnt,
                                                     int* __restrict__ offs,
                                                     int* __restrict__ esrc,
                                                     int n) {
    __shared__ int lcnt[512];
    __shared__ int sc[512];
    __shared__ int lexcl[512];
    int g = blockIdx.x;
    int node0 = g << BSHIFT;
    int t = threadIdx.x;
    lcnt[t] = 0;
    __syncthreads();
    int S = bbase[g];
    int Eg = bbase[g + 1];
    for (int i = S + t; i < Eg; i += 512)
        atomicAdd(&lcnt[pairs[i] >> 17], 1);
    __syncthreads();
    int v = lcnt[t];
    sc[t] = v;
    __syncthreads();
    for (int d = 1; d < 512; d <<= 1) {
        int u = (t >= d) ? sc[t - d] : 0;
        __syncthreads();
        sc[t] += u;
        __syncthreads();
    }
    int excl = sc[t] - v;
    lexcl[t] = excl;
    int nd = node0 + t;
    if (nd < n) {
        cnt[nd] = v;
        offs[nd] = S + excl;
    }
    __syncthreads();
    for (int i = S + t; i < Eg; i += 512) {
        int p = pairs[i];
        int pos = atomicAdd(&lexcl[p >> 17], 1);
        esrc[S + pos] = p & 0x1FFFF;
    }
}

// ---------- aggregate: one 16-lane group per node (4 nodes/wave) — round-3 proven ----------
#define ACC(c, r)                        \
    s[c][0] += *(half2v*)&(r).x;         \
    s[c][1] += *(half2v*)&(r).y;         \
    s[c][2] += *(half2v*)&(r).z;         \
    s[c][3] += *(half2v*)&(r).w;

__global__ void aggregate_kernel(const __half* __restrict__ feat, const int* __restrict__ esrc,
                                 const int* __restrict__ offs, const int* __restrict__ cnt,
                                 __half* __restrict__ agg, int n) {
    int wid = (blockIdx.x * blockDim.x + threadIdx.x) >> 6;
    int lane = threadIdx.x & 63;
    int grp = lane >> 4;            // 0..3: node slot within wave
    int l15 = lane & 15;
    int node = wid * 4 + grp;
    if (node >= n) return;
    int beg = offs[node];
    int deg = cnt[node];
    const _Float16* fbase = (const _Float16*)feat + l15 * 8;
    const int* ep = esrc + beg;

    half2v s[4][4];
#pragma unroll
    for (int c = 0; c < 4; c++)
#pragma unroll
        for (int k = 0; k < 4; k++) s[c][k] = (half2v)(_Float16)0;

    int j = 0;
    for (; j + 8 <= deg; j += 8) {
        int i0 = ep[j + 0], i1 = ep[j + 1], i2 = ep[j + 2], i3 = ep[j + 3];
        int i4 = ep[j + 4], i5 = ep[j + 5], i6 = ep[j + 6], i7 = ep[j + 7];
        uint4 r0 = *(const uint4*)(fbase + (size_t)i0 * DFEAT);
        uint4 r1 = *(const uint4*)(fbase + (size_t)i1 * DFEAT);
        uint4 r2 = *(const uint4*)(fbase + (size_t)i2 * DFEAT);
        uint4 r3 = *(const uint4*)(fbase + (size_t)i3 * DFEAT);
        uint4 r4 = *(const uint4*)(fbase + (size_t)i4 * DFEAT);
        uint4 r5 = *(const uint4*)(fbase + (size_t)i5 * DFEAT);
        uint4 r6 = *(const uint4*)(fbase + (size_t)i6 * DFEAT);
        uint4 r7 = *(const uint4*)(fbase + (size_t)i7 * DFEAT);
        ACC(0, r0) ACC(1, r1) ACC(2, r2) ACC(3, r3)
        ACC(0, r4) ACC(1, r5) ACC(2, r6) ACC(3, r7)
    }
    for (; j + 4 <= deg; j += 4) {
        int i0 = ep[j + 0], i1 = ep[j + 1], i2 = ep[j + 2], i3 = ep[j + 3];
        uint4 r0 = *(const uint4*)(fbase + (size_t)i0 * DFEAT);
        uint4 r1 = *(const uint4*)(fbase + (size_t)i1 * DFEAT);
        uint4 r2 = *(const uint4*)(fbase + (size_t)i2 * DFEAT);
        uint4 r3 = *(const uint4*)(fbase + (size_t)i3 * DFEAT);
        ACC(0, r0) ACC(1, r1) ACC(2, r2) ACC(3, r3)
    }
    if (j < deg) {
        int rem = deg - j;
        int i0 = ep[j];
        int i1 = ep[j + (rem > 1 ? 1 : 0)];
        int i2 = ep[j + (rem > 2 ? 2 : 0)];
        uint4 r0 = *(const uint4*)(fbase + (size_t)i0 * DFEAT);
        uint4 r1 = *(const uint4*)(fbase + (size_t)i1 * DFEAT);
        uint4 r2 = *(const uint4*)(fbase + (size_t)i2 * DFEAT);
        if (rem < 2) { r1.x = 0u; r1.y = 0u; r1.z = 0u; r1.w = 0u; }
        if (rem < 3) { r2.x = 0u; r2.y = 0u; r2.z = 0u; r2.w = 0u; }
        ACC(0, r0) ACC(1, r1) ACC(2, r2)
    }

    float scale = 1.0f / fmaxf((float)deg, 1.0f);
    float a[8];
#pragma unroll
    for (int k = 0; k < 4; k++) {
        a[2 * k]     = ((float)s[0][k].x + (float)s[1][k].x) + ((float)s[2][k].x + (float)s[3][k].x);
        a[2 * k + 1] = ((float)s[0][k].y + (float)s[1][k].y) + ((float)s[2][k].y + (float)s[3][k].y);
    }
    __half2 h0 = __floats2half2_rn(a[0] * scale, a[1] * scale);
    __half2 h1 = __floats2half2_rn(a[2] * scale, a[3] * scale);
    __half2 h2 = __floats2half2_rn(a[4] * scale, a[5] * scale);
    __half2 h3 = __floats2half2_rn(a[6] * scale, a[7] * scale);
    uint4 o;
    o.x = *(unsigned int*)&h0;
    o.y = *(unsigned int*)&h1;
    o.z = *(unsigned int*)&h2;
    o.w = *(unsigned int*)&h3;
    *(uint4*)(agg + (size_t)node * DFEAT + l15 * 8) = o;
}

// ---------- MFMA dual-GEMM, NO LDS: W fragments read straight from L1-resident fp16 W ----------
// W per matrix = 32 KB fp16 (= L1 size); every wave reads the same lines -> L1 hits.
// No barriers, no LDS -> occupancy VGPR-bound; Wl*agg and Wr*x MFMAs interleaved.
template <bool NORM_RELU>
__global__ __launch_bounds__(256) void gemm64_kernel(
    const __half* __restrict__ A1_, const __half* __restrict__ A2_,
    const __half* __restrict__ Wl16, const __half* __restrict__ Wr16,
    const float* __restrict__ bias, float* __restrict__ out32,
    __half* __restrict__ out16, int n) {
    const _Float16* A1 = (const _Float16*)A1_;
    const _Float16* A2 = (const _Float16*)A2_;
    const _Float16* wl = (const _Float16*)Wl16;
    const _Float16* wr = (const _Float16*)Wr16;

    const int lane = threadIdx.x & 63;
    const int w = threadIdx.x >> 6;       // wave 0..3
    const int quad = lane >> 4;
    const int l15 = lane & 15;
    const int i0 = blockIdx.x * 64 + w * 16;
    int r = i0 + l15;
    if (r >= n) r = n - 1;
    const int kq = quad * 8;

    // node fragments: agg row (B for Wl) and self row (B for Wr)
    half8 bf[4], xf[4];
#pragma unroll
    for (int k = 0; k < 4; k++) {
        bf[k] = *(const half8*)(A1 + (size_t)r * DFEAT + k * 32 + kq);
        xf[k] = *(const half8*)(A2 + (size_t)r * DFEAT + k * 32 + kq);
    }

    floatx4 acc[8];
#pragma unroll
    for (int ft = 0; ft < 8; ft++) acc[ft] = (floatx4){0.f, 0.f, 0.f, 0.f};

    const int wrow = l15 * DFEAT + kq;    // per-lane W base offset
#pragma unroll
    for (int kci = 0; kci < 4; kci++) {
#pragma unroll
        for (int ft = 0; ft < 8; ft++) {
            half8 al = *(const half8*)(wl + ft * 16 * DFEAT + wrow + kci * 32);
            half8 ar = *(const half8*)(wr + ft * 16 * DFEAT + wrow + kci * 32);
            acc[ft] = __builtin_amdgcn_mfma_f32_16x16x32_f16(al, bf[kci], acc[ft], 0, 0, 0);
            acc[ft] = __builtin_amdgcn_mfma_f32_16x16x32_f16(ar, xf[kci], acc[ft], 0, 0, 0);
        }
    }

    // ---- epilogue: bias (+ normalize + relu) + store ----
    int node = i0 + l15;
    float v[8][4];
#pragma unroll
    for (int ft = 0; ft < 8; ft++) {
        const float4 bq = *(const float4*)(bias + ft * 16 + quad * 4);
        v[ft][0] = acc[ft][0] + bq.x;
        v[ft][1] = acc[ft][1] + bq.y;
        v[ft][2] = acc[ft][2] + bq.z;
        v[ft][3] = acc[ft][3] + bq.w;
    }
    if (NORM_RELU) {
        float ss = 0.f;
#pragma unroll
        for (int ft = 0; ft < 8; ft++)
#pragma unroll
            for (int q = 0; q < 4; q++) ss = fmaf(v[ft][q], v[ft][q], ss);
        ss += __shfl_xor(ss, 16);
        ss += __shfl_xor(ss, 32);
        float inv = 1.0f / fmaxf(sqrtf(ss), 1e-12f);
#pragma unroll
        for (int ft = 0; ft < 8; ft++)
#pragma unroll
            for (int q = 0; q < 4; q++) v[ft][q] = fmaxf(v[ft][q] * inv, 0.0f);
    }
    if (node < n) {
        if (NORM_RELU) {
            __half* op = (__half*)out16 + (size_t)node * DFEAT + quad * 4;
#pragma unroll
            for (int ft = 0; ft < 8; ft++) {
                __half2 h01 = __floats2half2_rn(v[ft][0], v[ft][1]);
                __half2 h23 = __floats2half2_rn(v[ft][2], v[ft][3]);
                uint2 o;
                o.x = *(unsigned int*)&h01;
                o.y = *(unsigned int*)&h23;
                *(uint2*)(op + ft * 16) = o;
            }
        } else {
            float* op = out32 + (size_t)node * DFEAT + quad * 4;
#pragma unroll
            for (int ft = 0; ft < 8; ft++)
                *(float4*)(op + ft * 16) = make_float4(v[ft][0], v[ft][1], v[ft][2], v[ft][3]);
        }
    }
}

extern "C" void kernel_launch(void* const* d_in, const int* in_sizes, int n_in,
                              void* d_out, int out_size, void* d_ws, size_t ws_size,
                              hipStream_t stream) {
    const float* x = (const float*)d_in[0];
    const int* edge_index = (const int*)d_in[1];
    const float* W1l = (const float*)d_in[2];
    const float* b1 = (const float*)d_in[3];
    const float* W1r = (const float*)d_in[4];
    const float* W2l = (const float*)d_in[5];
    const float* b2 = (const float*)d_in[6];
    const float* W2r = (const float*)d_in[7];
    float* out = (float*)d_out;

    const int E = in_sizes[1] / 2;
    const int n = in_sizes[0] / DFEAT;  // 100000

    int* ws = (int*)d_ws;
    int* cnt = ws + WS_CNT;
    __half* w16 = (__half*)(ws + WS_W16);
    int* bcnt = ws + WS_BCNT;
    int* bbase = ws + WS_BBASE;
    int* bcur = ws + WS_BCUR;
    int* offs = ws + WS_OFFS;
    int* esrc = ws + WS_ESRC;
    int* pairs = ws + WS_AGGH;
    __half* aggh = (__half*)(ws + WS_AGGH);
    __half* casth = (__half*)(ws + WS_CASTH);

    const int* src = edge_index;
    const int* dst = edge_index + E;

    const int bpart = (E + SLAB - 1) / SLAB;        // 391
    const int total4 = n * DFEAT / 4;
    const int castblocks = (total4 + 255) / 256;    // 12500

    // per-matrix fp16 views (order: W1l, W1r, W2l, W2r)
    __half* w1l16 = w16;
    __half* w1r16 = w16 + 16384;
    __half* w2l16 = w16 + 32768;
    __half* w2r16 = w16 + 49152;

    hipMemsetAsync(bcnt, 0, NBUCK * sizeof(int), stream);

    prep_kernel<<<castblocks + 64 + bpart, 256, 0, stream>>>(
        x, casth, total4, dst, bcnt, W1l, W1r, W2l, W2r, w16, E, bpart, castblocks);
    bscan_kernel<<<1, 256, 0, stream>>>(bcnt, bbase, bcur, E);
    phase2_kernel<<<bpart, 256, 0, stream>>>(src, dst, bcur, pairs, E);
    phase3_kernel<<<NBUCK, 512, 0, stream>>>(pairs, bbase, cnt, offs, esrc, n);

    const int nwaves = (n + 3) / 4;
    const int aggb = (nwaves * 64 + 255) / 256;     // 6250
    const int gemmb = (n + 63) / 64;                // 1563

    // layer 1: agg(x_h) -> aggh; h = relu(normalize(aggh@W1l^T + b1 + x_h@W1r^T)) -> fp16 aggh
    // NOTE: pairs buffer (WS_AGGH region) is dead once phase3 completes; aggh reuses it.
    aggregate_kernel<<<aggb, 256, 0, stream>>>(casth, esrc, offs, cnt, aggh, n);
    gemm64_kernel<true><<<gemmb, 256, 0, stream>>>(aggh, casth, w1l16, w1r16, b1,
                                                   nullptr, aggh, n);

    // layer 2: agg(h) -> casth; out = casth@W2l^T + b2 + h@W2r^T (fp32 to d_out)
    aggregate_kernel<<<aggb, 256, 0, stream>>>(aggh, esrc, offs, cnt, casth, n);
    gemm64_kernel<false><<<gemmb, 256, 0, stream>>>(casth, aggh, w2l16, w2r16, b2,
                                                    out, nullptr, n);
}

// Round 10
// 329.691 us; speedup vs baseline: 2.8476x; 1.2279x over previous
//
#include <hip/hip_runtime.h>
#include <hip/hip_bf16.h>
#include <hip/hip_fp16.h>

#define N_NODES 100000
#define DFEAT 128
#define SLAB 4096         // edges per partition block
#define BSHIFT 9          // 512 nodes per bucket
#define NBUCK 196         // ceil(100000/512)

// ---------------- ws layout (4-byte units) ----------------
// cnt    [0      , 100000)   written by phase3
// w16    [100000 , 132768)   4x fp16 weight matrices (W1l,W1r,W2l,W2r)
// bcnt   [180000 , 180196)   per-bucket edge counts (global atomics; memset to 0)
// bbase  [180200 , 180397)   exclusive scan of bcnt (+ total at [196])
// bcur   [180400 , 180596)   allocation cursors per bucket
// offs   [200000 , 300096)   written by phase3
// esrc   [300608 , 1900608)
// pairs  [1900608, ...)      packed ((dst&511)<<17)|src; then fp16 agg1 / h
// casth  [8300608, 14700608) fp16 x_h, then agg2
#define WS_CNT      0
#define WS_W16      100000
#define WS_BCNT     180000
#define WS_BBASE    180200
#define WS_BCUR     180400
#define WS_OFFS     200000
#define WS_ESRC     300608
#define WS_AGGH     1900608
#define WS_CASTH    8300608

typedef _Float16 half8 __attribute__((ext_vector_type(8)));
typedef _Float16 half2v __attribute__((ext_vector_type(2)));
typedef float floatx4 __attribute__((ext_vector_type(4)));

// ---------- cast x -> fp16 (grid-stride, high MLP) ----------
__global__ __launch_bounds__(256) void cast_x_kernel(const float* __restrict__ x,
                                                     __half* __restrict__ xh, int total4) {
    int stride = gridDim.x * 256;
    for (int i = blockIdx.x * 256 + threadIdx.x; i < total4; i += stride) {
        float4 v = ((const float4*)x)[i];
        __half2 h01 = __floats2half2_rn(v.x, v.y);
        __half2 h23 = __floats2half2_rn(v.z, v.w);
        uint2 o;
        o.x = *(unsigned int*)&h01;
        o.y = *(unsigned int*)&h23;
        ((uint2*)xh)[i] = o;
    }
}

// ---------- cast 4 W matrices -> fp16 (64 blocks) ----------
__global__ __launch_bounds__(256) void cast_w_kernel(const float* __restrict__ W1l,
                                                     const float* __restrict__ W1r,
                                                     const float* __restrict__ W2l,
                                                     const float* __restrict__ W2r,
                                                     __half* __restrict__ w16) {
    int i = blockIdx.x * 256 + threadIdx.x;   // [0, 16384)
    int m = i >> 12;                           // matrix 0..3
    int off = i & 4095;
    const float* Wp = (m == 0) ? W1l : (m == 1) ? W1r : (m == 2) ? W2l : W2r;
    float4 v = ((const float4*)Wp)[off];
    __half2 h01 = __floats2half2_rn(v.x, v.y);
    __half2 h23 = __floats2half2_rn(v.z, v.w);
    uint2 o;
    o.x = *(unsigned int*)&h01;
    o.y = *(unsigned int*)&h23;
    ((uint2*)w16)[i] = o;
}

// ---------- slab bucket histogram (1024 threads: 4 iterations/slab) ----------
__global__ __launch_bounds__(1024) void hist_kernel(const int* __restrict__ dst,
                                                    int* __restrict__ bcnt, int E) {
    __shared__ int lh[NBUCK];
    int t = threadIdx.x;
    if (t < NBUCK) lh[t] = 0;
    __syncthreads();
    int s0 = blockIdx.x * SLAB, s1 = min(E, s0 + SLAB);
    for (int i = s0 + t; i < s1; i += 1024)
        atomicAdd(&lh[dst[i] >> BSHIFT], 1);
    __syncthreads();
    if (t < NBUCK && lh[t] > 0) atomicAdd(&bcnt[t], lh[t]);
}

// ---------- tiny bucket scan: bcnt[196] -> bbase (exclusive), init bcur ----------
__global__ void bscan_kernel(const int* __restrict__ bcnt, int* __restrict__ bbase,
                             int* __restrict__ bcur, int E) {
    __shared__ int s[256];
    int t = threadIdx.x;
    int v = (t < NBUCK) ? bcnt[t] : 0;
    s[t] = v;
    __syncthreads();
    for (int d = 1; d < 256; d <<= 1) {
        int u = (t >= d) ? s[t - d] : 0;
        __syncthreads();
        s[t] += u;
        __syncthreads();
    }
    if (t < NBUCK) {
        int excl = s[t] - v;
        bbase[t] = excl;
        bcur[t] = excl;
    }
    if (t == 0) bbase[NBUCK] = E;
}

// ---------- phase 2: LDS counting-sort slab by bucket (512 threads); packed pairs ----------
__global__ __launch_bounds__(512) void phase2_kernel(const int* __restrict__ src,
                                                     const int* __restrict__ dst,
                                                     int* __restrict__ bcur,
                                                     int* __restrict__ pairs,
                                                     int E) {
    __shared__ int lbase[NBUCK];
    __shared__ int lcur[NBUCK];
    __shared__ int lgb[NBUCK];
    __shared__ int sc[256];
    __shared__ int2 lp[SLAB];   // 32 KB
    int b = blockIdx.x;
    int t = threadIdx.x;
    if (t < NBUCK) lbase[t] = 0;
    __syncthreads();
    int s0 = b * SLAB, s1 = min(E, s0 + SLAB);
    for (int i = s0 + t; i < s1; i += 512)
        atomicAdd(&lbase[dst[i] >> BSHIFT], 1);
    __syncthreads();
    int v = (t < NBUCK) ? lbase[t] : 0;
    if (t < 256) sc[t] = v;
    __syncthreads();
    for (int d = 1; d < 256; d <<= 1) {
        int u = (t >= d && t < 256) ? sc[t - d] : 0;
        __syncthreads();
        if (t < 256) sc[t] += u;
        __syncthreads();
    }
    if (t < NBUCK) {
        int excl = sc[t] - v;
        lbase[t] = excl;
        lcur[t] = excl;
        lgb[t] = (v > 0) ? atomicAdd(&bcur[t], v) : 0;   // block's base within bucket
    }
    __syncthreads();
    for (int i = s0 + t; i < s1; i += 512) {
        int d = dst[i];
        int s = src[i];
        int bk = d >> BSHIFT;
        int pos = atomicAdd(&lcur[bk], 1);
        lp[pos] = make_int2(s, d);
    }
    __syncthreads();
    int m = s1 - s0;
    for (int i = t; i < m; i += 512) {
        int2 p = lp[i];
        int bk = p.y >> BSHIFT;
        pairs[lgb[bk] + (i - lbase[bk])] = ((p.y & 511) << 17) | p.x;
    }
}

// ---------- phase 3: per-bucket node hist + scan -> cnt/offs + CSR finalize (1024 thr) ----------
__global__ __launch_bounds__(1024) void phase3_kernel(const int* __restrict__ pairs,
                                                      const int* __restrict__ bbase,
                                                      int* __restrict__ cnt,
                                                      int* __restrict__ offs,
                                                      int* __restrict__ esrc,
                                                      int n) {
    __shared__ int lcnt[512];
    __shared__ int sc[512];
    __shared__ int lexcl[512];
    int g = blockIdx.x;
    int node0 = g << BSHIFT;
    int t = threadIdx.x;
    if (t < 512) lcnt[t] = 0;
    __syncthreads();
    int S = bbase[g];
    int Eg = bbase[g + 1];
    for (int i = S + t; i < Eg; i += 1024)
        atomicAdd(&lcnt[pairs[i] >> 17], 1);
    __syncthreads();
    int v = (t < 512) ? lcnt[t] : 0;
    if (t < 512) sc[t] = v;
    __syncthreads();
    for (int d = 1; d < 512; d <<= 1) {
        int u = (t >= d && t < 512) ? sc[t - d] : 0;
        __syncthreads();
        if (t < 512) sc[t] += u;
        __syncthreads();
    }
    if (t < 512) {
        int excl = sc[t] - v;
        lexcl[t] = excl;
        int nd = node0 + t;
        if (nd < n) {
            cnt[nd] = v;
            offs[nd] = S + excl;
        }
    }
    __syncthreads();
    for (int i = S + t; i < Eg; i += 1024) {
        int p = pairs[i];
        int pos = atomicAdd(&lexcl[p >> 17], 1);
        esrc[S + pos] = p & 0x1FFFF;
    }
}

// ---------- aggregate: one 16-lane group per node (4 nodes/wave) — at the gather wall ----------
#define ACC(c, r)                        \
    s[c][0] += *(half2v*)&(r).x;         \
    s[c][1] += *(half2v*)&(r).y;         \
    s[c][2] += *(half2v*)&(r).z;         \
    s[c][3] += *(half2v*)&(r).w;

__global__ void aggregate_kernel(const __half* __restrict__ feat, const int* __restrict__ esrc,
                                 const int* __restrict__ offs, const int* __restrict__ cnt,
                                 __half* __restrict__ agg, int n) {
    int wid = (blockIdx.x * blockDim.x + threadIdx.x) >> 6;
    int lane = threadIdx.x & 63;
    int grp = lane >> 4;            // 0..3: node slot within wave
    int l15 = lane & 15;
    int node = wid * 4 + grp;
    if (node >= n) return;
    int beg = offs[node];
    int deg = cnt[node];
    const _Float16* fbase = (const _Float16*)feat + l15 * 8;
    const int* ep = esrc + beg;

    half2v s[4][4];
#pragma unroll
    for (int c = 0; c < 4; c++)
#pragma unroll
        for (int k = 0; k < 4; k++) s[c][k] = (half2v)(_Float16)0;

    int j = 0;
    for (; j + 8 <= deg; j += 8) {
        int i0 = ep[j + 0], i1 = ep[j + 1], i2 = ep[j + 2], i3 = ep[j + 3];
        int i4 = ep[j + 4], i5 = ep[j + 5], i6 = ep[j + 6], i7 = ep[j + 7];
        uint4 r0 = *(const uint4*)(fbase + (size_t)i0 * DFEAT);
        uint4 r1 = *(const uint4*)(fbase + (size_t)i1 * DFEAT);
        uint4 r2 = *(const uint4*)(fbase + (size_t)i2 * DFEAT);
        uint4 r3 = *(const uint4*)(fbase + (size_t)i3 * DFEAT);
        uint4 r4 = *(const uint4*)(fbase + (size_t)i4 * DFEAT);
        uint4 r5 = *(const uint4*)(fbase + (size_t)i5 * DFEAT);
        uint4 r6 = *(const uint4*)(fbase + (size_t)i6 * DFEAT);
        uint4 r7 = *(const uint4*)(fbase + (size_t)i7 * DFEAT);
        ACC(0, r0) ACC(1, r1) ACC(2, r2) ACC(3, r3)
        ACC(0, r4) ACC(1, r5) ACC(2, r6) ACC(3, r7)
    }
    for (; j + 4 <= deg; j += 4) {
        int i0 = ep[j + 0], i1 = ep[j + 1], i2 = ep[j + 2], i3 = ep[j + 3];
        uint4 r0 = *(const uint4*)(fbase + (size_t)i0 * DFEAT);
        uint4 r1 = *(const uint4*)(fbase + (size_t)i1 * DFEAT);
        uint4 r2 = *(const uint4*)(fbase + (size_t)i2 * DFEAT);
        uint4 r3 = *(const uint4*)(fbase + (size_t)i3 * DFEAT);
        ACC(0, r0) ACC(1, r1) ACC(2, r2) ACC(3, r3)
    }
    if (j < deg) {
        int rem = deg - j;
        int i0 = ep[j];
        int i1 = ep[j + (rem > 1 ? 1 : 0)];
        int i2 = ep[j + (rem > 2 ? 2 : 0)];
        uint4 r0 = *(const uint4*)(fbase + (size_t)i0 * DFEAT);
        uint4 r1 = *(const uint4*)(fbase + (size_t)i1 * DFEAT);
        uint4 r2 = *(const uint4*)(fbase + (size_t)i2 * DFEAT);
        if (rem < 2) { r1.x = 0u; r1.y = 0u; r1.z = 0u; r1.w = 0u; }
        if (rem < 3) { r2.x = 0u; r2.y = 0u; r2.z = 0u; r2.w = 0u; }
        ACC(0, r0) ACC(1, r1) ACC(2, r2)
    }

    float scale = 1.0f / fmaxf((float)deg, 1.0f);
    float a[8];
#pragma unroll
    for (int k = 0; k < 4; k++) {
        a[2 * k]     = ((float)s[0][k].x + (float)s[1][k].x) + ((float)s[2][k].x + (float)s[3][k].x);
        a[2 * k + 1] = ((float)s[0][k].y + (float)s[1][k].y) + ((float)s[2][k].y + (float)s[3][k].y);
    }
    __half2 h0 = __floats2half2_rn(a[0] * scale, a[1] * scale);
    __half2 h1 = __floats2half2_rn(a[2] * scale, a[3] * scale);
    __half2 h2 = __floats2half2_rn(a[4] * scale, a[5] * scale);
    __half2 h3 = __floats2half2_rn(a[6] * scale, a[7] * scale);
    uint4 o;
    o.x = *(unsigned int*)&h0;
    o.y = *(unsigned int*)&h1;
    o.z = *(unsigned int*)&h2;
    o.w = *(unsigned int*)&h3;
    *(uint4*)(agg + (size_t)node * DFEAT + l15 * 8) = o;
}

// ---------- MFMA dual-GEMM: 64-node blocks, LDS-staged fp16 W (round-5 proven) ----------
template <bool NORM_RELU>
__global__ __launch_bounds__(256) void gemm64_kernel(
    const __half* __restrict__ A1_, const __half* __restrict__ A2_,
    const __half* __restrict__ Wl16, const __half* __restrict__ Wr16,
    const float* __restrict__ bias, float* __restrict__ out32,
    __half* __restrict__ out16, int n) {
    __shared__ __align__(16) _Float16 lw[128 * 136];   // 34.8 KB

    const _Float16* A1 = (const _Float16*)A1_;
    const _Float16* A2 = (const _Float16*)A2_;
    const _Float16* wl = (const _Float16*)Wl16;
    const _Float16* wr = (const _Float16*)Wr16;

    const int lane = threadIdx.x & 63;
    const int w = threadIdx.x >> 6;       // wave 0..3
    const int quad = lane >> 4;
    const int l15 = lane & 15;
    const int i0 = blockIdx.x * 64 + w * 16;
    int r = i0 + l15;
    if (r >= n) r = n - 1;
    const int kq = quad * 8;

    // prefetch B-fragments (agg rows) so they fly during Wl staging
    half8 bf[4];
#pragma unroll
    for (int k = 0; k < 4; k++)
        bf[k] = *(const half8*)(A1 + (size_t)r * DFEAT + k * 32 + kq);

    // stage Wl (fp16 copy, 8 uint4/thread)
    {
        int t = threadIdx.x;
        int row = t >> 1;
        int cb = (t & 1) * 64;
        const uint4* sp = (const uint4*)(wl + row * DFEAT + cb);
        uint4* dp = (uint4*)&lw[row * 136 + cb];
#pragma unroll
        for (int q = 0; q < 8; q++) dp[q] = sp[q];
    }
    __syncthreads();

    floatx4 acc[8];
#pragma unroll
    for (int ft = 0; ft < 8; ft++) acc[ft] = (floatx4){0.f, 0.f, 0.f, 0.f};

#pragma unroll
    for (int kci = 0; kci < 4; kci++) {
#pragma unroll
        for (int ft = 0; ft < 8; ft++) {
            half8 a = *(const half8*)&lw[(ft * 16 + l15) * 136 + kci * 32 + kq];
            acc[ft] = __builtin_amdgcn_mfma_f32_16x16x32_f16(a, bf[kci], acc[ft], 0, 0, 0);
        }
    }

    // prefetch root (self) fragments; they fly across the barrier/staging
    half8 xf[4];
#pragma unroll
    for (int k = 0; k < 4; k++)
        xf[k] = *(const half8*)(A2 + (size_t)r * DFEAT + k * 32 + kq);

    __syncthreads();   // all waves done reading Wl
    // stage Wr
    {
        int t = threadIdx.x;
        int row = t >> 1;
        int cb = (t & 1) * 64;
        const uint4* sp = (const uint4*)(wr + row * DFEAT + cb);
        uint4* dp = (uint4*)&lw[row * 136 + cb];
#pragma unroll
        for (int q = 0; q < 8; q++) dp[q] = sp[q];
    }
    __syncthreads();

#pragma unroll
    for (int kci = 0; kci < 4; kci++) {
#pragma unroll
        for (int ft = 0; ft < 8; ft++) {
            half8 a = *(const half8*)&lw[(ft * 16 + l15) * 136 + kci * 32 + kq];
            acc[ft] = __builtin_amdgcn_mfma_f32_16x16x32_f16(a, xf[kci], acc[ft], 0, 0, 0);
        }
    }

    // ---- epilogue: bias (+ normalize + relu) + store ----
    int node = i0 + l15;
    float v[8][4];
#pragma unroll
    for (int ft = 0; ft < 8; ft++) {
        const float4 bq = *(const float4*)(bias + ft * 16 + quad * 4);
        v[ft][0] = acc[ft][0] + bq.x;
        v[ft][1] = acc[ft][1] + bq.y;
        v[ft][2] = acc[ft][2] + bq.z;
        v[ft][3] = acc[ft][3] + bq.w;
    }
    if (NORM_RELU) {
        float ss = 0.f;
#pragma unroll
        for (int ft = 0; ft < 8; ft++)
#pragma unroll
            for (int q = 0; q < 4; q++) ss = fmaf(v[ft][q], v[ft][q], ss);
        ss += __shfl_xor(ss, 16);
        ss += __shfl_xor(ss, 32);
        float inv = 1.0f / fmaxf(sqrtf(ss), 1e-12f);
#pragma unroll
        for (int ft = 0; ft < 8; ft++)
#pragma unroll
            for (int q = 0; q < 4; q++) v[ft][q] = fmaxf(v[ft][q] * inv, 0.0f);
    }
    if (node < n) {
        if (NORM_RELU) {
            __half* op = (__half*)out16 + (size_t)node * DFEAT + quad * 4;
#pragma unroll
            for (int ft = 0; ft < 8; ft++) {
                __half2 h01 = __floats2half2_rn(v[ft][0], v[ft][1]);
                __half2 h23 = __floats2half2_rn(v[ft][2], v[ft][3]);
                uint2 o;
                o.x = *(unsigned int*)&h01;
                o.y = *(unsigned int*)&h23;
                *(uint2*)(op + ft * 16) = o;
            }
        } else {
            float* op = out32 + (size_t)node * DFEAT + quad * 4;
#pragma unroll
            for (int ft = 0; ft < 8; ft++)
                *(float4*)(op + ft * 16) = make_float4(v[ft][0], v[ft][1], v[ft][2], v[ft][3]);
        }
    }
}

extern "C" void kernel_launch(void* const* d_in, const int* in_sizes, int n_in,
                              void* d_out, int out_size, void* d_ws, size_t ws_size,
                              hipStream_t stream) {
    const float* x = (const float*)d_in[0];
    const int* edge_index = (const int*)d_in[1];
    const float* W1l = (const float*)d_in[2];
    const float* b1 = (const float*)d_in[3];
    const float* W1r = (const float*)d_in[4];
    const float* W2l = (const float*)d_in[5];
    const float* b2 = (const float*)d_in[6];
    const float* W2r = (const float*)d_in[7];
    float* out = (float*)d_out;

    const int E = in_sizes[1] / 2;
    const int n = in_sizes[0] / DFEAT;  // 100000

    int* ws = (int*)d_ws;
    int* cnt = ws + WS_CNT;
    __half* w16 = (__half*)(ws + WS_W16);
    int* bcnt = ws + WS_BCNT;
    int* bbase = ws + WS_BBASE;
    int* bcur = ws + WS_BCUR;
    int* offs = ws + WS_OFFS;
    int* esrc = ws + WS_ESRC;
    int* pairs = ws + WS_AGGH;
    __half* aggh = (__half*)(ws + WS_AGGH);
    __half* casth = (__half*)(ws + WS_CASTH);

    const int* src = edge_index;
    const int* dst = edge_index + E;

    const int bpart = (E + SLAB - 1) / SLAB;        // 391
    const int total4 = n * DFEAT / 4;               // 3.2M

    // per-matrix fp16 views (order: W1l, W1r, W2l, W2r)
    __half* w1l16 = w16;
    __half* w1r16 = w16 + 16384;
    __half* w2l16 = w16 + 32768;
    __half* w2r16 = w16 + 49152;

    hipMemsetAsync(bcnt, 0, NBUCK * sizeof(int), stream);

    cast_x_kernel<<<2048, 256, 0, stream>>>(x, casth, total4);
    cast_w_kernel<<<64, 256, 0, stream>>>(W1l, W1r, W2l, W2r, w16);
    hist_kernel<<<bpart, 1024, 0, stream>>>(dst, bcnt, E);
    bscan_kernel<<<1, 256, 0, stream>>>(bcnt, bbase, bcur, E);
    phase2_kernel<<<bpart, 512, 0, stream>>>(src, dst, bcur, pairs, E);
    phase3_kernel<<<NBUCK, 1024, 0, stream>>>(pairs, bbase, cnt, offs, esrc, n);

    const int nwaves = (n + 3) / 4;
    const int aggb = (nwaves * 64 + 255) / 256;     // 6250
    const int gemmb = (n + 63) / 64;                // 1563

    // layer 1: agg(x_h) -> aggh; h = relu(normalize(aggh@W1l^T + b1 + x_h@W1r^T)) -> fp16 aggh
    // NOTE: pairs buffer (WS_AGGH region) is dead once phase3 completes; aggh reuses it.
    aggregate_kernel<<<aggb, 256, 0, stream>>>(casth, esrc, offs, cnt, aggh, n);
    gemm64_kernel<true><<<gemmb, 256, 0, stream>>>(aggh, casth, w1l16, w1r16, b1,
                                                   nullptr, aggh, n);

    // layer 2: agg(h) -> casth; out = casth@W2l^T + b2 + h@W2r^T (fp32 to d_out)
    aggregate_kernel<<<aggb, 256, 0, stream>>>(aggh, esrc, offs, cnt, casth, n);
    gemm64_kernel<false><<<gemmb, 256, 0, stream>>>(casth, aggh, w2l16, w2r16, b2,
                                                    out, nullptr, n);
}